// Round 2
// baseline (163.186 us; speedup 1.0000x reference)
//
#include <hip/hip_runtime.h>
#include <math.h>

#define N_WL 262144

#define T_REF 273.15
#define P_REF 101325.0
#define C_LIGHT 299792458.0
#define K_B 1.380649e-23
#define N_AVO 6.02214076e+23

__constant__ float c_nu0[10]  = {254.0f, 280.0f, 310.0f, 940.0f, 1130.0f, 1380.0f, 1400.0f, 1600.0f, 2000.0f, 2700.0f};
__constant__ float c_str[10]  = {1.15e-17f, 5e-18f, 1.9e-19f, 2.5e-23f, 8.2e-24f, 1.8e-22f, 3.5e-25f, 7.8e-26f, 4.2e-24f, 1.2e-24f};
__constant__ float c_wid[10]  = {2.0f, 3.0f, 2.5f, 3.0f, 2.5f, 4.0f, 3.0f, 2.5f, 4.0f, 3.5f};
__constant__ float c_texp[10] = {0.05f, 0.04f, 0.03f, 0.4f, 0.35f, 0.45f, 0.5f, 0.48f, 0.52f, 0.49f};
__constant__ float c_mass[10] = {48.f, 48.f, 48.f, 18.f, 18.f, 18.f, 44.f, 44.f, 44.f, 44.f};
__constant__ int   c_cidx[10] = {0, 0, 0, 1, 1, 1, 2, 2, 2, 2};

__device__ __forceinline__ float siluf(float x)     { return x / (1.0f + __expf(-x)); }
__device__ __forceinline__ float sigmoidf(float x)  { return 1.0f / (1.0f + __expf(-x)); }
__device__ __forceinline__ float softplusf(float x) { return fmaxf(x, 0.0f) + log1pf(expf(-fabsf(x))); }

// Humlicek-style branched w(x,y) matching the reference (real part only).
// At runtime physics (y = gamma_L/sigma ~ 1e5) branch 1 is always taken,
// uniformly across the wave -> no divergence, no transcendentals.
__device__ __forceinline__ float voigt_w(float x, float y) {
    float ax = fabsf(x);
    float s  = ax + y;
    if (s >= 15.0f) {
        float ur = y * y - x * x;
        float ui = -2.0f * x * y;
        float dr = 0.5f + ur, di = ui;
        float nr = 0.5641896f * y, ni = 0.5641896f * (-x);
        float den = dr * dr + di * di;
        return (nr * dr + ni * di) / den;
    } else if (ax >= 5.5f) {
        float ur = y * y - x * x;
        float ui = -2.0f * x * y;
        float pr = 1.410474f + 0.5641896f * ur;
        float pi_ = 0.5641896f * ui;
        float tr = y, ti = -x;
        float nr = tr * pr - ti * pi_;
        float ni = tr * pi_ + ti * pr;
        float u2r = ur * ur - ui * ui;
        float u2i = 2.0f * ur * ui;
        float dr = 0.75f + 3.0f * ur + u2r;
        float di = 3.0f * ui + u2i;
        float den = dr * dr + di * di;
        return (nr * dr + ni * di) / den;
    } else {
        float x2 = x * x;
        return expf(-x2) * cosf(2.0f * x * y) * 0.5641895835477563f
             + (2.0f * y / 3.14159265358979f) * sinf(x2) / (x2 + y * y + 1e-10f);
    }
}

// ---------------- single fused kernel ----------------
// Phase A: every block redundantly computes the scalar setup (L2-hit reads,
//          deterministic -> identical results per block).
// Phase B: 2 wavelengths/thread via float2 (8 B/lane), 512 blocks x 256 thr
//          = 2 waves/SIMD; loads explicitly batched 8-deep and the mix_w3
//          loop hand-pipelined so ~8 wide loads stay in flight per wave
//          (the round-1 version serialized loads: VGPR=56, 1.1 TB/s).
__global__ __launch_bounds__(256) void GasAbs_fused_kernel(
    const float* __restrict__ wl,
    const float* __restrict__ Tp, const float* __restrict__ Pp,
    const float* __restrict__ o3, const float* __restrict__ h2o, const float* __restrict__ co2,
    const float* __restrict__ mix_w1, const float* __restrict__ mix_b1,
    const float* __restrict__ mix_w2, const float* __restrict__ mix_b2,
    const float* __restrict__ mix_w3, const float* __restrict__ mix_b3,
    const float* __restrict__ cont_w1, const float* __restrict__ cont_b1,
    const float* __restrict__ cont_w2, const float* __restrict__ cont_b2,
    float* __restrict__ out)
{
    __shared__ float s_nu0[10], s_isig[10], s_y[10], s_scale[10];
    __shared__ float s_h[32];
    __shared__ float s_feat[10];
    __shared__ float s_m1[64];
    __shared__ float s_m2[64];

    const int t = threadIdx.x;

    // ---- Phase A: redundant per-block scalar setup ----
    if (t < 10) {
        const double T = (double)Tp[0];
        const double P = (double)Pp[0];
        const float cc3[3] = {o3[0], h2o[0], co2[0]};
        double nu0 = (double)c_nu0[t];
        double sT  = (double)c_str[t] * pow(T_REF / (T + 1e-12), (double)c_texp[t]);
        double gL  = (double)c_wid[t] * (P / (P_REF + 1e-12)) * sqrt(T_REF / (T + 1e-12));
        double gD  = nu0 / C_LIGHT * sqrt(2.0 * K_B * T * N_AVO / ((double)c_mass[t] + 1e-12));
        double sig = gD / (sqrt(2.0 * log(2.0)) + 1e-12);
        s_nu0[t]   = (float)nu0;
        s_isig[t]  = (float)(1.0 / (sig + 1e-12));
        s_y[t]     = (float)(gL / (sig + 1e-12));
        s_scale[t] = (float)((double)cc3[c_cidx[t]] * sT / (sig * sqrt(M_PI) + 1e-12));
    }
    if (t < 32) {
        const double T = (double)Tp[0];
        const double P = (double)Pp[0];
        float cf[5];
        cf[0] = (float)(T / (T_REF + 1e-12));
        cf[1] = (float)(P / (P_REF + 1e-12));
        cf[2] = h2o[0];
        cf[3] = 1.0f;
        cf[4] = 0.0f;
        float a = cont_b1[t];
        #pragma unroll
        for (int k = 0; k < 5; k++) a = fmaf(cf[k], cont_w1[k * 32 + t], a);
        s_h[t] = siluf(a);
    }
    __syncthreads();

    if (t < 8) {
        float w = wl[t];
        float c = cont_b2[t];
        #pragma unroll
        for (int j = 0; j < 32; j++) c = fmaf(s_h[j], cont_w2[(size_t)j * N_WL + t], c);
        float cross = softplusf(c);
        #pragma unroll
        for (int l = 0; l < 10; l++) {
            float x = (w - s_nu0[l]) * s_isig[l];
            cross = fmaf(s_scale[l], voigt_w(x, s_y[l]), cross);
        }
        s_feat[2 + t] = cross;
    }
    if (t == 0) {
        const double T = (double)Tp[0];
        const double P = (double)Pp[0];
        s_feat[0] = (float)(T / (T_REF + 1e-12));
        s_feat[1] = (float)(P / (P_REF + 1e-12));
    }
    __syncthreads();

    if (t < 64) {
        float a = mix_b1[t];
        #pragma unroll
        for (int k = 0; k < 10; k++) a = fmaf(s_feat[k], mix_w1[k * 64 + t], a);
        s_m1[t] = siluf(a);
    }
    __syncthreads();

    if (t < 64) {
        float a = mix_b2[t];
        #pragma unroll
        for (int k = 0; k < 64; k++) a = fmaf(s_m1[k], mix_w2[k * 64 + t], a);
        s_m2[t] = siluf(a);
    }
    __syncthreads();

    // ---- Phase B: 2 elements/thread, batched + pipelined loads ----
    const int i0 = (blockIdx.x * 256 + t) * 2;

    const float2 w2 = *reinterpret_cast<const float2*>(wl + i0);
    float2 ac = *reinterpret_cast<const float2*>(cont_b2 + i0);
    float2 am = *reinterpret_cast<const float2*>(mix_b3 + i0);

    // continuum: 32-deep dot, 4 batches of 8 loads each (8 in flight).
    #pragma unroll
    for (int jb = 0; jb < 32; jb += 8) {
        float2 v[8];
        #pragma unroll
        for (int u = 0; u < 8; u++)
            v[u] = *reinterpret_cast<const float2*>(cont_w2 + (size_t)(jb + u) * N_WL + i0);
        #pragma unroll
        for (int u = 0; u < 8; u++) {
            const float hj = s_h[jb + u];
            ac.x = fmaf(hj, v[u].x, ac.x);
            ac.y = fmaf(hj, v[u].y, ac.y);
        }
    }

    // Issue the first mix_w3 batch BEFORE the Voigt VALU section so the
    // loads fly under the compute.
    float2 vb[8];
    #pragma unroll
    for (int u = 0; u < 8; u++)
        vb[u] = *reinterpret_cast<const float2*>(mix_w3 + (size_t)u * N_WL + i0);

    float cr0 = softplusf(ac.x);
    float cr1 = softplusf(ac.y);

    #pragma unroll
    for (int l = 0; l < 10; l++) {
        const float nu0 = s_nu0[l], isig = s_isig[l], yy = s_y[l], sc = s_scale[l];
        cr0 = fmaf(sc, voigt_w((w2.x - nu0) * isig, yy), cr0);
        cr1 = fmaf(sc, voigt_w((w2.y - nu0) * isig, yy), cr1);
    }

    // mixing gate: 64-deep dot, hand-pipelined 8-deep (issue b+1, consume b).
    #pragma unroll
    for (int jb = 0; jb < 64; jb += 8) {
        float2 vn[8];
        if (jb + 8 < 64) {
            #pragma unroll
            for (int u = 0; u < 8; u++)
                vn[u] = *reinterpret_cast<const float2*>(mix_w3 + (size_t)(jb + 8 + u) * N_WL + i0);
        }
        #pragma unroll
        for (int u = 0; u < 8; u++) {
            const float mj = s_m2[jb + u];
            am.x = fmaf(mj, vb[u].x, am.x);
            am.y = fmaf(mj, vb[u].y, am.y);
        }
        #pragma unroll
        for (int u = 0; u < 8; u++) vb[u] = vn[u];
    }

    float2 o;
    o.x = cr0 * (0.95f + 0.1f * sigmoidf(am.x));
    o.y = cr1 * (0.95f + 0.1f * sigmoidf(am.y));
    *reinterpret_cast<float2*>(out + i0) = o;
}

extern "C" void kernel_launch(void* const* d_in, const int* in_sizes, int n_in,
                              void* d_out, int out_size, void* d_ws, size_t ws_size,
                              hipStream_t stream) {
    const float* wl      = (const float*)d_in[0];
    const float* Tp      = (const float*)d_in[1];
    const float* Pp      = (const float*)d_in[2];
    const float* o3      = (const float*)d_in[3];
    const float* h2o     = (const float*)d_in[4];
    const float* co2     = (const float*)d_in[5];
    const float* mix_w1  = (const float*)d_in[6];
    const float* mix_b1  = (const float*)d_in[7];
    const float* mix_w2  = (const float*)d_in[8];
    const float* mix_b2  = (const float*)d_in[9];
    const float* mix_w3  = (const float*)d_in[10];
    const float* mix_b3  = (const float*)d_in[11];
    const float* cont_w1 = (const float*)d_in[12];
    const float* cont_b1 = (const float*)d_in[13];
    const float* cont_w2 = (const float*)d_in[14];
    const float* cont_b2 = (const float*)d_in[15];
    float* out = (float*)d_out;

    const int threads = 256;
    const int blocks  = N_WL / (threads * 2);  // 512 blocks, 2 wl/thread
    GasAbs_fused_kernel<<<blocks, threads, 0, stream>>>(
        wl, Tp, Pp, o3, h2o, co2,
        mix_w1, mix_b1, mix_w2, mix_b2, mix_w3, mix_b3,
        cont_w1, cont_b1, cont_w2, cont_b2, out);
}

// Round 3
// 149.981 us; speedup vs baseline: 1.0880x; 1.0880x over previous
//
#include <hip/hip_runtime.h>
#include <math.h>

#define N_WL 262144

#define T_REF 273.15
#define P_REF 101325.0
#define C_LIGHT 299792458.0
#define K_B 1.380649e-23
#define N_AVO 6.02214076e+23

__constant__ float c_nu0[10]  = {254.0f, 280.0f, 310.0f, 940.0f, 1130.0f, 1380.0f, 1400.0f, 1600.0f, 2000.0f, 2700.0f};
__constant__ float c_str[10]  = {1.15e-17f, 5e-18f, 1.9e-19f, 2.5e-23f, 8.2e-24f, 1.8e-22f, 3.5e-25f, 7.8e-26f, 4.2e-24f, 1.2e-24f};
__constant__ float c_wid[10]  = {2.0f, 3.0f, 2.5f, 3.0f, 2.5f, 4.0f, 3.0f, 2.5f, 4.0f, 3.5f};
__constant__ float c_texp[10] = {0.05f, 0.04f, 0.03f, 0.4f, 0.35f, 0.45f, 0.5f, 0.48f, 0.52f, 0.49f};
__constant__ float c_mass[10] = {48.f, 48.f, 48.f, 18.f, 18.f, 18.f, 44.f, 44.f, 44.f, 44.f};
__constant__ int   c_cidx[10] = {0, 0, 0, 1, 1, 1, 2, 2, 2, 2};

__device__ __forceinline__ float siluf(float x)     { return x / (1.0f + __expf(-x)); }
__device__ __forceinline__ float sigmoidf(float x)  { return 1.0f / (1.0f + __expf(-x)); }
__device__ __forceinline__ float softplusf(float x) { return fmaxf(x, 0.0f) + log1pf(expf(-fabsf(x))); }

// Humlicek-style branched w(x,y) matching the reference (real part only).
// At runtime physics (y = gamma_L/sigma ~ 1e5) branch 1 is always taken,
// uniformly across the wave -> no divergence, no transcendentals.
__device__ __forceinline__ float voigt_w(float x, float y) {
    float ax = fabsf(x);
    float s  = ax + y;
    if (s >= 15.0f) {
        float ur = y * y - x * x;
        float ui = -2.0f * x * y;
        float dr = 0.5f + ur, di = ui;
        float nr = 0.5641896f * y, ni = 0.5641896f * (-x);
        float den = dr * dr + di * di;
        return (nr * dr + ni * di) / den;
    } else if (ax >= 5.5f) {
        float ur = y * y - x * x;
        float ui = -2.0f * x * y;
        float pr = 1.410474f + 0.5641896f * ur;
        float pi_ = 0.5641896f * ui;
        float tr = y, ti = -x;
        float nr = tr * pr - ti * pi_;
        float ni = tr * pi_ + ti * pr;
        float u2r = ur * ur - ui * ui;
        float u2i = 2.0f * ur * ui;
        float dr = 0.75f + 3.0f * ur + u2r;
        float di = 3.0f * ui + u2i;
        float den = dr * dr + di * di;
        return (nr * dr + ni * di) / den;
    } else {
        float x2 = x * x;
        return expf(-x2) * cosf(2.0f * x * y) * 0.5641895835477563f
             + (2.0f * y / 3.14159265358979f) * sinf(x2) / (x2 + y * y + 1e-10f);
    }
}

// ---------------- single fused kernel ----------------
// Phase A: every block redundantly computes the scalar setup (identical
//          inputs -> identical results; weight reads are L2 hits).
// Phase B: 1 wavelength/thread (max TLP: 1024 blocks = 16 waves/CU), the
//          96 weight rows (32 cont_w2 + 64 mix_w3) streamed through ONE
//          16-deep rotating register pipeline. asm-memory fences every 8
//          rows pin the issue/consume order so the compiler cannot
//          collapse the pipeline (R2 showed source batching alone is
//          ignored: VGPR=132 but BW unchanged at 1.07 TB/s).
__global__ __launch_bounds__(256) void GasAbs_fused_kernel(
    const float* __restrict__ wl,
    const float* __restrict__ Tp, const float* __restrict__ Pp,
    const float* __restrict__ o3, const float* __restrict__ h2o, const float* __restrict__ co2,
    const float* __restrict__ mix_w1, const float* __restrict__ mix_b1,
    const float* __restrict__ mix_w2, const float* __restrict__ mix_b2,
    const float* __restrict__ mix_w3, const float* __restrict__ mix_b3,
    const float* __restrict__ cont_w1, const float* __restrict__ cont_b1,
    const float* __restrict__ cont_w2, const float* __restrict__ cont_b2,
    float* __restrict__ out)
{
    __shared__ float s_nu0[10], s_isig[10], s_y[10], s_scale[10];
    __shared__ float s_h[32];
    __shared__ float s_feat[10];
    __shared__ float s_m1[64];
    __shared__ float s_m2[64];

    const int t = threadIdx.x;

    // ---- Phase A: redundant per-block scalar setup ----
    if (t < 10) {
        const double T = (double)Tp[0];
        const double P = (double)Pp[0];
        const float cc3[3] = {o3[0], h2o[0], co2[0]};
        double nu0 = (double)c_nu0[t];
        double sT  = (double)c_str[t] * pow(T_REF / (T + 1e-12), (double)c_texp[t]);
        double gL  = (double)c_wid[t] * (P / (P_REF + 1e-12)) * sqrt(T_REF / (T + 1e-12));
        double gD  = nu0 / C_LIGHT * sqrt(2.0 * K_B * T * N_AVO / ((double)c_mass[t] + 1e-12));
        double sig = gD / (sqrt(2.0 * log(2.0)) + 1e-12);
        s_nu0[t]   = (float)nu0;
        s_isig[t]  = (float)(1.0 / (sig + 1e-12));
        s_y[t]     = (float)(gL / (sig + 1e-12));
        s_scale[t] = (float)((double)cc3[c_cidx[t]] * sT / (sig * sqrt(M_PI) + 1e-12));
    }
    if (t < 32) {
        const double T = (double)Tp[0];
        const double P = (double)Pp[0];
        float cf[5];
        cf[0] = (float)(T / (T_REF + 1e-12));
        cf[1] = (float)(P / (P_REF + 1e-12));
        cf[2] = h2o[0];
        cf[3] = 1.0f;
        cf[4] = 0.0f;
        float a = cont_b1[t];
        #pragma unroll
        for (int k = 0; k < 5; k++) a = fmaf(cf[k], cont_w1[k * 32 + t], a);
        s_h[t] = siluf(a);
    }
    __syncthreads();

    if (t < 8) {
        float w = wl[t];
        float c = cont_b2[t];
        #pragma unroll
        for (int j = 0; j < 32; j++) c = fmaf(s_h[j], cont_w2[(size_t)j * N_WL + t], c);
        float cross = softplusf(c);
        #pragma unroll
        for (int l = 0; l < 10; l++) {
            float x = (w - s_nu0[l]) * s_isig[l];
            cross = fmaf(s_scale[l], voigt_w(x, s_y[l]), cross);
        }
        s_feat[2 + t] = cross;
    }
    if (t == 0) {
        const double T = (double)Tp[0];
        const double P = (double)Pp[0];
        s_feat[0] = (float)(T / (T_REF + 1e-12));
        s_feat[1] = (float)(P / (P_REF + 1e-12));
    }
    __syncthreads();

    if (t < 64) {
        float a = mix_b1[t];
        #pragma unroll
        for (int k = 0; k < 10; k++) a = fmaf(s_feat[k], mix_w1[k * 64 + t], a);
        s_m1[t] = siluf(a);
    }
    __syncthreads();

    if (t < 64) {
        float a = mix_b2[t];
        #pragma unroll
        for (int k = 0; k < 64; k++) a = fmaf(s_m1[k], mix_w2[k * 64 + t], a);
        s_m2[t] = siluf(a);
    }
    __syncthreads();

    // ---- Phase B: 1 element/thread, unified 96-row 16-deep pipeline ----
    const int i = blockIdx.x * 256 + t;
    const float* __restrict__ wp = cont_w2 + i;   // 32 rows, stride N_WL
    const float* __restrict__ mp = mix_w3  + i;   // 64 rows, stride N_WL

    // oldest loads first: scalars this thread needs
    const float wv = wl[i];
    const float bc = cont_b2[i];
    const float bm = mix_b3[i];

    // prologue: fill the 16-slot pipeline (rows 0..15 of cont_w2)
    float buf[16];
    #pragma unroll
    for (int k = 0; k < 16; k++)
        buf[k] = wp[(size_t)k * N_WL];
    asm volatile("" ::: "memory");   // pin: prologue issues stay above voigt

    // Voigt line sum runs under the 16 in-flight loads (pure VALU).
    float vsum = 0.0f;
    #pragma unroll
    for (int l = 0; l < 10; l++) {
        const float x = (wv - s_nu0[l]) * s_isig[l];
        vsum = fmaf(s_scale[l], voigt_w(x, s_y[l]), vsum);
    }

    float acc_c = bc;
    float acc_m = bm;

    // 96 rows: consume row k, immediately re-issue row k+16 into the freed
    // slot. Fences every 8 rows pin cross-group order: issues of rows
    // k+16 cannot sink below consumes of rows k+8.. -> vmcnt stays ~15.
    #pragma unroll
    for (int g = 0; g < 12; g++) {
        #pragma unroll
        for (int u = 0; u < 8; u++) {
            const int k = g * 8 + u;
            const float v = buf[k & 15];
            if (k < 32) acc_c = fmaf(s_h[k],      v, acc_c);
            else        acc_m = fmaf(s_m2[k - 32], v, acc_m);
            const int kn = k + 16;
            if (kn < 96)
                buf[k & 15] = (kn < 32) ? wp[(size_t)kn * N_WL]
                                        : mp[(size_t)(kn - 32) * N_WL];
        }
        asm volatile("" ::: "memory");
    }

    const float cross = softplusf(acc_c) + vsum;
    out[i] = cross * (0.95f + 0.1f * sigmoidf(acc_m));
}

extern "C" void kernel_launch(void* const* d_in, const int* in_sizes, int n_in,
                              void* d_out, int out_size, void* d_ws, size_t ws_size,
                              hipStream_t stream) {
    const float* wl      = (const float*)d_in[0];
    const float* Tp      = (const float*)d_in[1];
    const float* Pp      = (const float*)d_in[2];
    const float* o3      = (const float*)d_in[3];
    const float* h2o     = (const float*)d_in[4];
    const float* co2     = (const float*)d_in[5];
    const float* mix_w1  = (const float*)d_in[6];
    const float* mix_b1  = (const float*)d_in[7];
    const float* mix_w2  = (const float*)d_in[8];
    const float* mix_b2  = (const float*)d_in[9];
    const float* mix_w3  = (const float*)d_in[10];
    const float* mix_b3  = (const float*)d_in[11];
    const float* cont_w1 = (const float*)d_in[12];
    const float* cont_b1 = (const float*)d_in[13];
    const float* cont_w2 = (const float*)d_in[14];
    const float* cont_b2 = (const float*)d_in[15];
    float* out = (float*)d_out;

    const int threads = 256;
    const int blocks  = N_WL / threads;   // 1024 blocks, 1 wl/thread
    GasAbs_fused_kernel<<<blocks, threads, 0, stream>>>(
        wl, Tp, Pp, o3, h2o, co2,
        mix_w1, mix_b1, mix_w2, mix_b2, mix_w3, mix_b3,
        cont_w1, cont_b1, cont_w2, cont_b2, out);
}